// Round 1
// baseline (764.764 us; speedup 1.0000x reference)
//
#include <hip/hip_runtime.h>
#include <hip/hip_cooperative_groups.h>

namespace cg = cooperative_groups;

#define NN 50000
#define NE 800000
#define FD 128
#define FDH 64            // FD/2 packed bf16 pairs
#define FA 32
#define NG 128
#define EETOT (NE + NN)
#define NBLK ((NN + 255) / 256)   // 196 scan tiles
#define FEPB 2048                 // fill: edges per chunk
#define FNCH ((EETOT + FEPB - 1) / FEPB)
#define NPXCD 6250                // nodes per XCD-parity bin
#define CBG 1024                  // cooperative grid blocks
#define CBT (CBG * 256)

typedef __attribute__((ext_vector_type(8))) short short8;
typedef __attribute__((ext_vector_type(4))) float f32x4;

// ---------- bf16 helpers ----------
__device__ __forceinline__ float bfbits(unsigned short u) {
    return __uint_as_float(((unsigned int)u) << 16);
}
__device__ __forceinline__ float bflo(unsigned int p) { return __uint_as_float(p << 16); }
__device__ __forceinline__ float bfhi(unsigned int p) { return __uint_as_float(p & 0xffff0000u); }
__device__ __forceinline__ unsigned short f2bf(float f) {   // RNE
    unsigned int u = __float_as_uint(f);
    unsigned int r = u + 0x7FFFu + ((u >> 16) & 1u);
    return (unsigned short)(r >> 16);
}
__device__ __forceinline__ unsigned int packbf(float a, float b) {
    return (unsigned int)f2bf(a) | ((unsigned int)f2bf(b) << 16);
}
__device__ __forceinline__ int ld_idx(const int* p, int i, int is64) {
    return is64 ? p[2 * i] : p[i];
}

// ---------- sentinels ----------
__global__ __launch_bounds__(128) void mark_kernel(float* out, float v) {
    out[threadIdx.x] = v;
}

// ---------- all dtype probes, wave-parallel ----------
__global__ __launch_bounds__(256) void flags_kernel(
        const unsigned int* x, const int* ei, const int* batch,
        const unsigned int* addf, const unsigned int* w1, const unsigned int* b1,
        const unsigned int* w2, const unsigned int* b2, const unsigned int* fc1w,
        const unsigned int* fc1b, const unsigned int* fc2w, const unsigned int* fc2b,
        int* flags) {
    int w = threadIdx.x >> 6, lane = threadIdx.x & 63;
    const unsigned int* tp[12] = {x, 0, 0, addf, w1, b1, w2, b2, fc1w, fc1b, fc2w, fc2b};
    const int nw[12] = {64, 0, 0, 64, 64, 64, 64, 64, 64, 64, 64, 1};
    for (int idx = w; idx < 12; idx += 4) {
        const unsigned int* p = tp[idx];
        if (!p) continue;
        unsigned int wv = (lane < nw[idx]) ? p[lane] : 0u;
        int nzp = (wv != 0u) ? 1 : 0;
        unsigned int e = (wv >> 7) & 0xFFu;
        int hitp = (nzp && e >= 100u && e <= 140u) ? 1 : 0;
        int nz = __popcll(__ballot(nzp));
        int hits = __popcll(__ballot(hitp));
        if (lane == 0) flags[idx] = (nz < 8) ? 1 : (hits * 4 >= nz * 3);
    }
    if (w == 1) {
        int v = (lane < 32) ? ei[2 * lane + 1] : 0;
        unsigned long long m = __ballot(v != 0);
        if (lane == 0) flags[12] = (m == 0ull) ? 1 : 0;
    }
    if (w == 2 && lane == 0) flags[13] = (batch[NN - 1] == 0) ? 1 : 0;
}

// ---------- prep: weights + params + zero degi (x handled inline by gemm) ----------
__global__ __launch_bounds__(256) void prep(
        const void* addf, const void* w1, const void* b1, const void* w2,
        const void* b2, const void* fc1w, const void* fc1b, const void* fc2w,
        const void* fc2b, unsigned int* W1t, unsigned int* W2t,
        float* addff, float* b1f, float* b2f, float* fc1wf, float* fc1bf,
        float* fc2wf, float* fc2bf, const int* flags, int* degi) {
    int b = blockIdx.x;
    if (b < 64) {
        int rel = b * 256 + threadIdx.x;             // [0,16384)
        const void* src = (rel < 8192) ? w1 : w2;
        unsigned int* dst = (rel < 8192) ? W1t : W2t;
        int flag = (rel < 8192) ? flags[4] : flags[6];
        int rr = rel & 8191;
        int n = rr >> 6, kk = rr & 63;
        float lo, hi;
        if (flag) {
            const unsigned short* s = (const unsigned short*)src;
            lo = bfbits(s[(2 * kk) * FD + n]);
            hi = bfbits(s[(2 * kk + 1) * FD + n]);
        } else {
            const float* s = (const float*)src;
            lo = s[(2 * kk) * FD + n];
            hi = s[(2 * kk + 1) * FD + n];
        }
        dst[rr] = packbf(lo, hi);
    } else if (b < 163) {
        int i = (b - 64) * 256 + threadIdx.x;        // [0,25344)
        const void* src; float* dst; int flag; int rel;
        if      (i < 4096)  { src = addf; dst = addff; flag = flags[3];  rel = i; }
        else if (i < 4224)  { src = b1;   dst = b1f;   flag = flags[5];  rel = i - 4096; }
        else if (i < 4352)  { src = b2;   dst = b2f;   flag = flags[7];  rel = i - 4224; }
        else if (i < 24832) { src = fc1w; dst = fc1wf; flag = flags[8];  rel = i - 4352; }
        else if (i < 24960) { src = fc1b; dst = fc1bf; flag = flags[9];  rel = i - 24832; }
        else if (i < 25216) { src = fc2w; dst = fc2wf; flag = flags[10]; rel = i - 24960; }
        else if (i < 25218) { src = fc2b; dst = fc2bf; flag = flags[11]; rel = i - 25216; }
        else return;
        if (flag) dst[rel] = bfbits(((const unsigned short*)src)[rel]);
        else      dst[rel] = ((const float*)src)[rel];
    } else {
        int i = (b - 163) * 256 + threadIdx.x;
        if (i < NN) degi[i] = 0;
    }
}

// ---------- cooperative fused CSR build: deg -> scan -> rowstart/gstart -> fill ----------
__global__ __launch_bounds__(256, 4) void coop_build(
        const int* ei, const int* batch, const int* flags,
        int* degi, float* dinv, int* escan, int* bsum,
        int* rowstart, int* cursor, int* gstart,
        int* s32, int* d32, unsigned int* cv) {
    cg::grid_group grid = cg::this_grid();
    __shared__ int sh[256];
    int tid = blockIdx.x * 256 + threadIdx.x;
    int b = blockIdx.x;
    int is64 = flags[12];

    // phase A: degree + int32 edge compaction (degi pre-zeroed by prep)
    for (int e = tid; e < NE; e += CBT) {
        int s = ld_idx(ei, e, is64);
        int d = ld_idx(ei, NE + e, is64);
        s32[e] = s;
        d32[e] = d;
        atomicAdd(&degi[d], 1);
    }
    grid.sync();

    // phase B1: per-tile inclusive scan + dinv
    if (b < NBLK) {
        int i = b * 256 + threadIdx.x;
        int d = (i < NN) ? degi[i] : 0;
        if (i < NN) dinv[i] = rsqrtf((float)(d + 1));
        int v = (i < NN) ? d + 1 : 0;
        sh[threadIdx.x] = v;
        __syncthreads();
        for (int off = 1; off < 256; off <<= 1) {
            int a = ((int)threadIdx.x >= off) ? sh[threadIdx.x - off] : 0;
            __syncthreads();
            sh[threadIdx.x] += a;
            __syncthreads();
        }
        if (i < NN) escan[i] = sh[threadIdx.x] - v;
        if (threadIdx.x == 255) bsum[b] = sh[255];
    }
    grid.sync();

    // phase B2: block 0 turns bsum into exclusive tile offsets
    if (b == 0) {
        int t = threadIdx.x;
        int v = (t < NBLK) ? bsum[t] : 0;
        sh[t] = v;
        __syncthreads();
        for (int off = 1; off < 256; off <<= 1) {
            int a = (t >= off) ? sh[t - off] : 0;
            __syncthreads();
            sh[t] += a;
            __syncthreads();
        }
        if (t < NBLK) bsum[t] = sh[t] - v;           // exclusive
    }
    grid.sync();

    // phase B3: rowstart/cursor + gstart
    if (b < NBLK) {
        int i = b * 256 + threadIdx.x;
        if (i < NN) {
            int r = escan[i] + bsum[b];
            rowstart[i] = r;
            cursor[i]   = r;
        }
        if (i == 0) rowstart[NN] = EETOT;
        if (i < NN) {
            int is64b = flags[13];
            int bc = ld_idx(batch, i, is64b);
            if (i == 0) {
                for (int g = 0; g <= bc; ++g) gstart[g] = 0;
            } else {
                int bp = ld_idx(batch, i - 1, is64b);
                for (int g = bp + 1; g <= bc; ++g) gstart[g] = i;
            }
            if (i == NN - 1) {
                for (int g = bc + 1; g <= NG; ++g) gstart[g] = NN;
            }
        }
    }
    grid.sync();

    // phase C: fill with XCD-affinity dst binning (int32 indices)
    for (int vb = b; vb < FNCH * 8; vb += CBG) {     // CBG%8==0 keeps par==XCD
        int chunk = vb >> 3;
        int par   = vb & 7;
        int base  = chunk * FEPB;
        #pragma unroll
        for (int k = 0; k < FEPB / 256; ++k) {
            int e = base + k * 256 + threadIdx.x;
            if (e >= EETOT) break;
            int s, d;
            if (e < NE) { d = d32[e]; s = -1; }
            else        { s = d = e - NE; }
            if (d / NPXCD != par) continue;
            if (s < 0) s = s32[e];
            int pos = atomicAdd(&cursor[d], 1);
            cv[pos] = (unsigned int)s | ((unsigned int)f2bf(dinv[s] * dinv[d]) << 16);
        }
    }
}

// ---------- fallback path (non-cooperative), unchanged logic ----------
__global__ __launch_bounds__(256) void deg_kernel(const int* ei, const int* flags,
                                                  int* deg) {
    int e = blockIdx.x * 256 + threadIdx.x;
    int is64 = flags[12];
    if (e < NE) atomicAdd(&deg[ld_idx(ei, NE + e, is64)], 1);
}

__global__ __launch_bounds__(256) void scan1(const int* deg, float* dinv,
                                             int* escan, int* bsum) {
    __shared__ int sh[256];
    int i = blockIdx.x * 256 + threadIdx.x;
    int d = (i < NN) ? deg[i] : 0;
    if (i < NN) dinv[i] = rsqrtf((float)(d + 1));
    int v = (i < NN) ? d + 1 : 0;
    sh[threadIdx.x] = v;
    __syncthreads();
    for (int off = 1; off < 256; off <<= 1) {
        int a = ((int)threadIdx.x >= off) ? sh[threadIdx.x - off] : 0;
        __syncthreads();
        sh[threadIdx.x] += a;
        __syncthreads();
    }
    if (i < NN) escan[i] = sh[threadIdx.x] - v;
    if (threadIdx.x == 255) bsum[blockIdx.x] = sh[255];
}

__global__ __launch_bounds__(256) void scan3(const int* escan, const int* bsum,
        const int* batch, const int* flags, int* rowstart, int* cursor, int* gstart) {
    __shared__ int sb[256];
    int t = threadIdx.x;
    int v = (t < NBLK) ? bsum[t] : 0;
    sb[t] = v;
    __syncthreads();
    for (int off = 1; off < 256; off <<= 1) {
        int a = (t >= off) ? sb[t - off] : 0;
        __syncthreads();
        sb[t] += a;
        __syncthreads();
    }
    int boff = (blockIdx.x == 0) ? 0 : sb[blockIdx.x - 1];
    int i = blockIdx.x * 256 + t;
    if (i < NN) {
        int r = escan[i] + boff;
        rowstart[i] = r;
        cursor[i]   = r;
    }
    if (i == 0) rowstart[NN] = EETOT;
    if (i < NN) {
        int is64 = flags[13];
        int bc = ld_idx(batch, i, is64);
        if (i == 0) {
            for (int g = 0; g <= bc; ++g) gstart[g] = 0;
        } else {
            int bp = ld_idx(batch, i - 1, is64);
            for (int g = bp + 1; g <= bc; ++g) gstart[g] = i;
        }
        if (i == NN - 1) {
            for (int g = bc + 1; g <= NG; ++g) gstart[g] = NN;
        }
    }
}

__global__ __launch_bounds__(256) void fill_kernel(const int* ei, const int* flags,
        const float* dinv, int* cursor, unsigned int* cv) {
    int chunk = blockIdx.x >> 3;
    int par   = blockIdx.x & 7;
    int base  = chunk * FEPB;
    int is64  = flags[12];
    #pragma unroll
    for (int k = 0; k < FEPB / 256; ++k) {
        int e = base + k * 256 + threadIdx.x;
        if (e >= EETOT) break;
        int s, d;
        if (e < NE) { d = ld_idx(ei, NE + e, is64); s = -1; }
        else        { s = d = e - NE; }
        if (d / NPXCD != par) continue;
        if (s < 0) s = ld_idx(ei, e, is64);
        int pos = atomicAdd(&cursor[d], 1);
        cv[pos] = (unsigned int)s | ((unsigned int)f2bf(dinv[s] * dinv[d]) << 16);
    }
}

// ---------- MFMA GEMM with optional inline fp32->bf16 A conversion ----------
__global__ __launch_bounds__(256) void gemm_mfma(const void* __restrict__ Av,
        const unsigned int* __restrict__ Wt, unsigned short* __restrict__ C,
        const int* flags, int maybe_f32) {
    int wave = threadIdx.x >> 6;
    int lane = threadIdx.x & 63;
    int quad = lane >> 4;
    int l16  = lane & 15;
    int mbase = blockIdx.x * 64 + wave * 16;
    int ra = mbase + l16;
    if (ra >= NN) ra = NN - 1;
    short8 af[4];
    bool f32in = maybe_f32 && !flags[0];
    if (!f32in) {
        const uint4* Arow = (const uint4*)((const unsigned int*)Av + (size_t)ra * FDH);
        #pragma unroll
        for (int kk = 0; kk < 4; ++kk) {
            uint4 v = Arow[kk * 4 + quad];
            af[kk] = *(short8*)&v;
        }
    } else {
        const float* Arow = (const float*)Av + (size_t)ra * FD;
        #pragma unroll
        for (int kk = 0; kk < 4; ++kk) {
            const float4* p = (const float4*)(Arow + (kk * 4 + quad) * 8);
            float4 u = p[0], v = p[1];
            uint4 q;
            q.x = packbf(u.x, u.y); q.y = packbf(u.z, u.w);
            q.z = packbf(v.x, v.y); q.w = packbf(v.z, v.w);
            af[kk] = *(short8*)&q;
        }
    }
    #pragma unroll
    for (int nt = 0; nt < 8; ++nt) {
        int n = nt * 16 + l16;
        const uint4* Wrow = (const uint4*)(Wt + (size_t)n * FDH);
        f32x4 acc = {0.f, 0.f, 0.f, 0.f};
        #pragma unroll
        for (int kk = 0; kk < 4; ++kk) {
            uint4 wv = Wrow[kk * 4 + quad];
            short8 bf = *(short8*)&wv;
            acc = __builtin_amdgcn_mfma_f32_16x16x32_bf16(af[kk], bf, acc, 0, 0, 0);
        }
        int row0 = mbase + quad * 4;
        #pragma unroll
        for (int reg = 0; reg < 4; ++reg) {
            int r = row0 + reg;
            if (r < NN) C[(size_t)r * FD + nt * 16 + l16] = f2bf(acc[reg]);
        }
    }
}

// ---------- CSR aggregation (bf16 gather, unroll 8) + bias + relu -> bf16 ----------
__global__ __launch_bounds__(256) void aggregate_kernel(const unsigned int* Hb,
        const unsigned int* cv, const int* rowstart, const float* bias,
        unsigned int* outb) {
    int n = blockIdx.x * 4 + (threadIdx.x >> 6);
    int cp = threadIdx.x & 63;
    if (n >= NN) return;
    int jb = rowstart[n], je = rowstart[n + 1];
    float acc0 = 0.f, acc1 = 0.f;
    int j = jb;
    for (; j + 7 < je; j += 8) {
        unsigned int rr[8], hh[8];
        #pragma unroll
        for (int k = 0; k < 8; ++k) rr[k] = cv[j + k];
        #pragma unroll
        for (int k = 0; k < 8; ++k) hh[k] = Hb[(size_t)(rr[k] & 0xFFFFu) * FDH + cp];
        #pragma unroll
        for (int k = 0; k < 8; ++k) {
            float v = bfbits((unsigned short)(rr[k] >> 16));
            acc0 += v * bflo(hh[k]);
            acc1 += v * bfhi(hh[k]);
        }
    }
    for (; j + 3 < je; j += 4) {
        unsigned int rr[4], hh[4];
        #pragma unroll
        for (int k = 0; k < 4; ++k) rr[k] = cv[j + k];
        #pragma unroll
        for (int k = 0; k < 4; ++k) hh[k] = Hb[(size_t)(rr[k] & 0xFFFFu) * FDH + cp];
        #pragma unroll
        for (int k = 0; k < 4; ++k) {
            float v = bfbits((unsigned short)(rr[k] >> 16));
            acc0 += v * bflo(hh[k]);
            acc1 += v * bfhi(hh[k]);
        }
    }
    for (; j < je; ++j) {
        unsigned int r = cv[j];
        unsigned int h = Hb[(size_t)(r & 0xFFFFu) * FDH + cp];
        float v = bfbits((unsigned short)(r >> 16));
        acc0 += v * bflo(h);
        acc1 += v * bfhi(h);
    }
    acc0 = fmaxf(acc0 + bias[2 * cp], 0.f);
    acc1 = fmaxf(acc1 + bias[2 * cp + 1], 0.f);
    outb[(size_t)n * FDH + cp] = packbf(acc0, acc1);
}

// ---------- fused mean-pool + MLP head (one block per graph) ----------
__global__ __launch_bounds__(256) void poolhead(const unsigned int* Hb,
        const int* gstart, const float* addf, const float* fc1w, const float* fc1b,
        const float* fc2w, const float* fc2b, const int* flags, void* outp) {
    int g = blockIdx.x;
    int t = threadIdx.x;
    int q = t >> 6, w = t & 63;
    int s = gstart[g], e = gstart[g + 1];
    float a0 = 0.f, a1 = 0.f;
    #pragma unroll 4
    for (int n = s + q; n < e; n += 4) {
        unsigned int h = Hb[(size_t)n * FDH + w];
        a0 += bflo(h);
        a1 += bfhi(h);
    }
    __shared__ float pp[4][FD];
    __shared__ float z[FD + FA];
    __shared__ float h[FD];
    pp[q][2 * w]     = a0;
    pp[q][2 * w + 1] = a1;
    __syncthreads();
    if (t < FD) {
        float cnt = (float)(e - s);
        if (cnt < 1.0f) cnt = 1.0f;
        z[t] = (pp[0][t] + pp[1][t] + pp[2][t] + pp[3][t]) / cnt;
    }
    if (t >= FD && t < FD + FA) z[t] = addf[g * FA + (t - FD)];
    __syncthreads();
    if (t < FD) {
        float acc = fc1b[t];
        #pragma unroll 4
        for (int k = 0; k < FD + FA; ++k)
            acc += z[k] * fc1w[k * FD + t];
        h[t] = fmaxf(acc, 0.f);
    }
    __syncthreads();
    if (t < 2) {
        float o = fc2b[t];
        for (int j = 0; j < FD; ++j) o += h[j] * fc2w[j * 2 + t];
        if (flags[0]) ((unsigned short*)outp)[g * 2 + t] = f2bf(o);
        else          ((float*)outp)[g * 2 + t] = o;
    }
}

extern "C" void kernel_launch(void* const* d_in, const int* in_sizes, int n_in,
                              void* d_out, int out_size, void* d_ws, size_t ws_size,
                              hipStream_t stream) {
    (void)out_size;

    if (n_in != 12) {
        hipLaunchKernelGGL(mark_kernel, dim3(1), dim3(128), 0, stream,
                           (float*)d_out, 2000.0f);
        return;
    }
    const int exp_sizes[12] = {6400000, 1600000, 50000, 4096, 16384, 128,
                               16384, 128, 20480, 128, 256, 2};
    for (int i = 0; i < 12; ++i) {
        if (in_sizes[i] != exp_sizes[i]) {
            hipLaunchKernelGGL(mark_kernel, dim3(1), dim3(128), 0, stream,
                               (float*)d_out, 3000.0f + 100.0f * i);
            return;
        }
    }

    size_t off = 0;
    char* base = (char*)d_ws;
#define WSALLOC(ptr, type, nbytes) \
    type* ptr = (type*)(base + off); off += (((size_t)(nbytes)) + 255) & ~(size_t)255;
    WSALLOC(bufA,  unsigned int, (size_t)NN * FDH * 4)
    WSALLOC(bufB,  unsigned int, (size_t)NN * FDH * 4)
    WSALLOC(dinv,  float, (size_t)NN * 4)
    WSALLOC(degi,  int,   (size_t)NN * 4)
    WSALLOC(rowst, int,   (size_t)(NN + 1) * 4)
    WSALLOC(cursor,int,   (size_t)NN * 4)
    WSALLOC(escan, int,   (size_t)NN * 4)
    WSALLOC(bsum,  int,   (size_t)NBLK * 4)
    WSALLOC(cv,    unsigned int, (size_t)EETOT * 4)
    WSALLOC(gstart,int,   (size_t)(NG + 1) * 4)
    WSALLOC(s32,   int,   (size_t)NE * 4)
    WSALLOC(d32,   int,   (size_t)NE * 4)
    WSALLOC(W1t,   unsigned int, (size_t)FD * FDH * 4)
    WSALLOC(W2t,   unsigned int, (size_t)FD * FDH * 4)
    WSALLOC(b1f,   float, FD * 4)
    WSALLOC(b2f,   float, FD * 4)
    WSALLOC(addff, float, (size_t)NG * FA * 4)
    WSALLOC(fc1wf, float, (size_t)(FD + FA) * FD * 4)
    WSALLOC(fc1bf, float, FD * 4)
    WSALLOC(fc2wf, float, FD * 2 * 4)
    WSALLOC(fc2bf, float, 2 * 4)
    WSALLOC(flags, int, 16 * 4)
#undef WSALLOC
    if (ws_size < off) {
        hipLaunchKernelGGL(mark_kernel, dim3(1), dim3(128), 0, stream,
                           (float*)d_out, 1000.0f);
        return;
    }

    const int* ei    = (const int*)d_in[1];
    const int* batch = (const int*)d_in[2];

    hipLaunchKernelGGL(flags_kernel, dim3(1), dim3(256), 0, stream,
                       (const unsigned int*)d_in[0], ei, batch,
                       (const unsigned int*)d_in[3], (const unsigned int*)d_in[4],
                       (const unsigned int*)d_in[5], (const unsigned int*)d_in[6],
                       (const unsigned int*)d_in[7], (const unsigned int*)d_in[8],
                       (const unsigned int*)d_in[9], (const unsigned int*)d_in[10],
                       (const unsigned int*)d_in[11], flags);

    hipLaunchKernelGGL(prep, dim3(359), dim3(256), 0, stream,
                       d_in[3], d_in[4], d_in[5], d_in[6], d_in[7],
                       d_in[8], d_in[9], d_in[10], d_in[11],
                       W1t, W2t, addff, b1f, b2f, fc1wf, fc1bf,
                       fc2wf, fc2bf, flags, degi);

    {
        const int* eiA = ei;
        const int* batchA = batch;
        const int* flagsA = flags;
        void* cbArgs[13] = {
            (void*)&eiA, (void*)&batchA, (void*)&flagsA,
            (void*)&degi, (void*)&dinv, (void*)&escan, (void*)&bsum,
            (void*)&rowst, (void*)&cursor, (void*)&gstart,
            (void*)&s32, (void*)&d32, (void*)&cv
        };
        hipError_t cerr = hipLaunchCooperativeKernel(
            reinterpret_cast<void*>(coop_build), dim3(CBG), dim3(256),
            cbArgs, 0, stream);
        if (cerr != hipSuccess) {
            // fallback: original 4-kernel CSR build
            hipLaunchKernelGGL(deg_kernel, dim3((NE + 255) / 256), dim3(256), 0,
                               stream, ei, flags, degi);
            hipLaunchKernelGGL(scan1, dim3(NBLK), dim3(256), 0, stream,
                               degi, dinv, escan, bsum);
            hipLaunchKernelGGL(scan3, dim3(NBLK), dim3(256), 0, stream,
                               escan, bsum, batch, flags, rowst, cursor, gstart);
            hipLaunchKernelGGL(fill_kernel, dim3(FNCH * 8), dim3(256), 0, stream,
                               ei, flags, dinv, cursor, cv);
        }
    }

    hipLaunchKernelGGL(gemm_mfma, dim3((NN + 63) / 64), dim3(256), 0, stream,
                       d_in[0], W1t, (unsigned short*)bufA, flags, 1);
    hipLaunchKernelGGL(aggregate_kernel, dim3((NN + 3) / 4), dim3(256), 0, stream,
                       bufA, cv, rowst, b1f, bufB);
    hipLaunchKernelGGL(gemm_mfma, dim3((NN + 63) / 64), dim3(256), 0, stream,
                       bufB, W2t, (unsigned short*)bufA, flags, 0);
    hipLaunchKernelGGL(aggregate_kernel, dim3((NN + 3) / 4), dim3(256), 0, stream,
                       bufA, cv, rowst, b2f, bufB);

    hipLaunchKernelGGL(poolhead, dim3(NG), dim3(256), 0, stream,
                       bufB, gstart, addff, fc1wf, fc1bf, fc2wf, fc2bf,
                       flags, d_out);
}

// Round 2
// 310.996 us; speedup vs baseline: 2.4591x; 2.4591x over previous
//
#include <hip/hip_runtime.h>

#define NN 50000
#define NE 800000
#define FD 128
#define FDH 64            // FD/2 packed bf16 pairs
#define FA 32
#define NG 128
#define EETOT (NE + NN)
#define NBLK ((NN + 255) / 256)   // 196 scan tiles
#define FEPB 2048                 // fill: edges per chunk
#define FNCH ((EETOT + FEPB - 1) / FEPB)
#define NPXCD 6250                // nodes per XCD-parity bin

typedef __attribute__((ext_vector_type(8))) short short8;
typedef __attribute__((ext_vector_type(4))) float f32x4;

// ---------- bf16 helpers ----------
__device__ __forceinline__ float bfbits(unsigned short u) {
    return __uint_as_float(((unsigned int)u) << 16);
}
__device__ __forceinline__ float bflo(unsigned int p) { return __uint_as_float(p << 16); }
__device__ __forceinline__ float bfhi(unsigned int p) { return __uint_as_float(p & 0xffff0000u); }
__device__ __forceinline__ unsigned short f2bf(float f) {   // RNE
    unsigned int u = __float_as_uint(f);
    unsigned int r = u + 0x7FFFu + ((u >> 16) & 1u);
    return (unsigned short)(r >> 16);
}
__device__ __forceinline__ unsigned int packbf(float a, float b) {
    return (unsigned int)f2bf(a) | ((unsigned int)f2bf(b) << 16);
}
__device__ __forceinline__ int ld_idx(const int* p, int i, int is64) {
    return is64 ? p[2 * i] : p[i];
}

// ---------- sentinels ----------
__global__ __launch_bounds__(128) void mark_kernel(float* out, float v) {
    out[threadIdx.x] = v;
}

// ---------- all dtype probes, wave-parallel ----------
__global__ __launch_bounds__(256) void flags_kernel(
        const unsigned int* x, const int* ei, const int* batch,
        const unsigned int* addf, const unsigned int* w1, const unsigned int* b1,
        const unsigned int* w2, const unsigned int* b2, const unsigned int* fc1w,
        const unsigned int* fc1b, const unsigned int* fc2w, const unsigned int* fc2b,
        int* flags) {
    int w = threadIdx.x >> 6, lane = threadIdx.x & 63;
    const unsigned int* tp[12] = {x, 0, 0, addf, w1, b1, w2, b2, fc1w, fc1b, fc2w, fc2b};
    const int nw[12] = {64, 0, 0, 64, 64, 64, 64, 64, 64, 64, 64, 1};
    for (int idx = w; idx < 12; idx += 4) {
        const unsigned int* p = tp[idx];
        if (!p) continue;
        unsigned int wv = (lane < nw[idx]) ? p[lane] : 0u;
        int nzp = (wv != 0u) ? 1 : 0;
        unsigned int e = (wv >> 7) & 0xFFu;
        int hitp = (nzp && e >= 100u && e <= 140u) ? 1 : 0;
        int nz = __popcll(__ballot(nzp));
        int hits = __popcll(__ballot(hitp));
        if (lane == 0) flags[idx] = (nz < 8) ? 1 : (hits * 4 >= nz * 3);
    }
    if (w == 1) {
        int v = (lane < 32) ? ei[2 * lane + 1] : 0;
        unsigned long long m = __ballot(v != 0);
        if (lane == 0) flags[12] = (m == 0ull) ? 1 : 0;
    }
    if (w == 2 && lane == 0) flags[13] = (batch[NN - 1] == 0) ? 1 : 0;
}

// ---------- prep: weights + params + zero degi (x handled inline by gemm) ----------
__global__ __launch_bounds__(256) void prep(
        const void* addf, const void* w1, const void* b1, const void* w2,
        const void* b2, const void* fc1w, const void* fc1b, const void* fc2w,
        const void* fc2b, unsigned int* W1t, unsigned int* W2t,
        float* addff, float* b1f, float* b2f, float* fc1wf, float* fc1bf,
        float* fc2wf, float* fc2bf, const int* flags, int* degi) {
    int b = blockIdx.x;
    if (b < 64) {
        int rel = b * 256 + threadIdx.x;             // [0,16384)
        const void* src = (rel < 8192) ? w1 : w2;
        unsigned int* dst = (rel < 8192) ? W1t : W2t;
        int flag = (rel < 8192) ? flags[4] : flags[6];
        int rr = rel & 8191;
        int n = rr >> 6, kk = rr & 63;
        float lo, hi;
        if (flag) {
            const unsigned short* s = (const unsigned short*)src;
            lo = bfbits(s[(2 * kk) * FD + n]);
            hi = bfbits(s[(2 * kk + 1) * FD + n]);
        } else {
            const float* s = (const float*)src;
            lo = s[(2 * kk) * FD + n];
            hi = s[(2 * kk + 1) * FD + n];
        }
        dst[rr] = packbf(lo, hi);
    } else if (b < 163) {
        int i = (b - 64) * 256 + threadIdx.x;        // [0,25344)
        const void* src; float* dst; int flag; int rel;
        if      (i < 4096)  { src = addf; dst = addff; flag = flags[3];  rel = i; }
        else if (i < 4224)  { src = b1;   dst = b1f;   flag = flags[5];  rel = i - 4096; }
        else if (i < 4352)  { src = b2;   dst = b2f;   flag = flags[7];  rel = i - 4224; }
        else if (i < 24832) { src = fc1w; dst = fc1wf; flag = flags[8];  rel = i - 4352; }
        else if (i < 24960) { src = fc1b; dst = fc1bf; flag = flags[9];  rel = i - 24832; }
        else if (i < 25216) { src = fc2w; dst = fc2wf; flag = flags[10]; rel = i - 24960; }
        else if (i < 25218) { src = fc2b; dst = fc2bf; flag = flags[11]; rel = i - 25216; }
        else return;
        if (flag) dst[rel] = bfbits(((const unsigned short*)src)[rel]);
        else      dst[rel] = ((const float*)src)[rel];
    } else {
        int i = (b - 163) * 256 + threadIdx.x;
        if (i < NN) degi[i] = 0;
    }
}

// ---------- degree + int32 edge compaction ----------
__global__ __launch_bounds__(256) void deg_kernel(const int* ei, const int* flags,
                                                  int* deg, int* s32, int* d32) {
    int e = blockIdx.x * 256 + threadIdx.x;
    int is64 = flags[12];
    if (e < NE) {
        int s = ld_idx(ei, e, is64);
        int d = ld_idx(ei, NE + e, is64);
        s32[e] = s;
        d32[e] = d;
        atomicAdd(&deg[d], 1);
    }
}

// ---------- scan phase 1 (+ dinv fused) ----------
__global__ __launch_bounds__(256) void scan1(const int* deg, float* dinv,
                                             int* escan, int* bsum) {
    __shared__ int sh[256];
    int i = blockIdx.x * 256 + threadIdx.x;
    int d = (i < NN) ? deg[i] : 0;
    if (i < NN) dinv[i] = rsqrtf((float)(d + 1));
    int v = (i < NN) ? d + 1 : 0;
    sh[threadIdx.x] = v;
    __syncthreads();
    for (int off = 1; off < 256; off <<= 1) {
        int a = ((int)threadIdx.x >= off) ? sh[threadIdx.x - off] : 0;
        __syncthreads();
        sh[threadIdx.x] += a;
        __syncthreads();
    }
    if (i < NN) escan[i] = sh[threadIdx.x] - v;
    if (threadIdx.x == 255) bsum[blockIdx.x] = sh[255];
}

// ---------- scan phase 2+3 + gstart fused ----------
__global__ __launch_bounds__(256) void scan3(const int* escan, const int* bsum,
        const int* batch, const int* flags, int* rowstart, int* cursor, int* gstart) {
    __shared__ int sb[256];
    int t = threadIdx.x;
    int v = (t < NBLK) ? bsum[t] : 0;
    sb[t] = v;
    __syncthreads();
    for (int off = 1; off < 256; off <<= 1) {
        int a = (t >= off) ? sb[t - off] : 0;
        __syncthreads();
        sb[t] += a;
        __syncthreads();
    }
    int boff = (blockIdx.x == 0) ? 0 : sb[blockIdx.x - 1];
    int i = blockIdx.x * 256 + t;
    if (i < NN) {
        int r = escan[i] + boff;
        rowstart[i] = r;
        cursor[i]   = r;
    }
    if (i == 0) rowstart[NN] = EETOT;
    if (i < NN) {
        int is64 = flags[13];
        int bc = ld_idx(batch, i, is64);
        if (i == 0) {
            for (int g = 0; g <= bc; ++g) gstart[g] = 0;
        } else {
            int bp = ld_idx(batch, i - 1, is64);
            for (int g = bp + 1; g <= bc; ++g) gstart[g] = i;
        }
        if (i == NN - 1) {
            for (int g = bc + 1; g <= NG; ++g) gstart[g] = NN;
        }
    }
}

// ---------- CSR fill with XCD-affinity dst binning (int32 indices) ----------
__global__ __launch_bounds__(256) void fill_kernel(const int* s32, const int* d32,
        const float* dinv, int* cursor, unsigned int* cv) {
    int chunk = blockIdx.x >> 3;
    int par   = blockIdx.x & 7;
    int base  = chunk * FEPB;
    #pragma unroll
    for (int k = 0; k < FEPB / 256; ++k) {
        int e = base + k * 256 + threadIdx.x;
        if (e >= EETOT) break;
        int s, d;
        if (e < NE) { d = d32[e]; s = -1; }
        else        { s = d = e - NE; }
        if (d / NPXCD != par) continue;
        if (s < 0) s = s32[e];
        int pos = atomicAdd(&cursor[d], 1);
        cv[pos] = (unsigned int)s | ((unsigned int)f2bf(dinv[s] * dinv[d]) << 16);
    }
}

// ---------- MFMA GEMM with optional inline fp32->bf16 A conversion ----------
__global__ __launch_bounds__(256) void gemm_mfma(const void* __restrict__ Av,
        const unsigned int* __restrict__ Wt, unsigned short* __restrict__ C,
        const int* flags, int maybe_f32) {
    int wave = threadIdx.x >> 6;
    int lane = threadIdx.x & 63;
    int quad = lane >> 4;
    int l16  = lane & 15;
    int mbase = blockIdx.x * 64 + wave * 16;
    int ra = mbase + l16;
    if (ra >= NN) ra = NN - 1;
    short8 af[4];
    bool f32in = maybe_f32 && !flags[0];
    if (!f32in) {
        const uint4* Arow = (const uint4*)((const unsigned int*)Av + (size_t)ra * FDH);
        #pragma unroll
        for (int kk = 0; kk < 4; ++kk) {
            uint4 v = Arow[kk * 4 + quad];
            af[kk] = *(short8*)&v;
        }
    } else {
        const float* Arow = (const float*)Av + (size_t)ra * FD;
        #pragma unroll
        for (int kk = 0; kk < 4; ++kk) {
            const float4* p = (const float4*)(Arow + (kk * 4 + quad) * 8);
            float4 u = p[0], v = p[1];
            uint4 q;
            q.x = packbf(u.x, u.y); q.y = packbf(u.z, u.w);
            q.z = packbf(v.x, v.y); q.w = packbf(v.z, v.w);
            af[kk] = *(short8*)&q;
        }
    }
    #pragma unroll
    for (int nt = 0; nt < 8; ++nt) {
        int n = nt * 16 + l16;
        const uint4* Wrow = (const uint4*)(Wt + (size_t)n * FDH);
        f32x4 acc = {0.f, 0.f, 0.f, 0.f};
        #pragma unroll
        for (int kk = 0; kk < 4; ++kk) {
            uint4 wv = Wrow[kk * 4 + quad];
            short8 bf = *(short8*)&wv;
            acc = __builtin_amdgcn_mfma_f32_16x16x32_bf16(af[kk], bf, acc, 0, 0, 0);
        }
        int row0 = mbase + quad * 4;
        #pragma unroll
        for (int reg = 0; reg < 4; ++reg) {
            int r = row0 + reg;
            if (r < NN) C[(size_t)r * FD + nt * 16 + l16] = f2bf(acc[reg]);
        }
    }
}

// ---------- CSR aggregation (bf16 gather, unroll 8) + bias + relu -> bf16 ----------
__global__ __launch_bounds__(256) void aggregate_kernel(const unsigned int* Hb,
        const unsigned int* cv, const int* rowstart, const float* bias,
        unsigned int* outb) {
    int n = blockIdx.x * 4 + (threadIdx.x >> 6);
    int cp = threadIdx.x & 63;
    if (n >= NN) return;
    int jb = rowstart[n], je = rowstart[n + 1];
    float acc0 = 0.f, acc1 = 0.f;
    int j = jb;
    for (; j + 7 < je; j += 8) {
        unsigned int rr[8], hh[8];
        #pragma unroll
        for (int k = 0; k < 8; ++k) rr[k] = cv[j + k];
        #pragma unroll
        for (int k = 0; k < 8; ++k) hh[k] = Hb[(size_t)(rr[k] & 0xFFFFu) * FDH + cp];
        #pragma unroll
        for (int k = 0; k < 8; ++k) {
            float v = bfbits((unsigned short)(rr[k] >> 16));
            acc0 += v * bflo(hh[k]);
            acc1 += v * bfhi(hh[k]);
        }
    }
    for (; j + 3 < je; j += 4) {
        unsigned int rr[4], hh[4];
        #pragma unroll
        for (int k = 0; k < 4; ++k) rr[k] = cv[j + k];
        #pragma unroll
        for (int k = 0; k < 4; ++k) hh[k] = Hb[(size_t)(rr[k] & 0xFFFFu) * FDH + cp];
        #pragma unroll
        for (int k = 0; k < 4; ++k) {
            float v = bfbits((unsigned short)(rr[k] >> 16));
            acc0 += v * bflo(hh[k]);
            acc1 += v * bfhi(hh[k]);
        }
    }
    for (; j < je; ++j) {
        unsigned int r = cv[j];
        unsigned int h = Hb[(size_t)(r & 0xFFFFu) * FDH + cp];
        float v = bfbits((unsigned short)(r >> 16));
        acc0 += v * bflo(h);
        acc1 += v * bfhi(h);
    }
    acc0 = fmaxf(acc0 + bias[2 * cp], 0.f);
    acc1 = fmaxf(acc1 + bias[2 * cp + 1], 0.f);
    outb[(size_t)n * FDH + cp] = packbf(acc0, acc1);
}

// ---------- fused mean-pool + MLP head (one block per graph) ----------
__global__ __launch_bounds__(256) void poolhead(const unsigned int* Hb,
        const int* gstart, const float* addf, const float* fc1w, const float* fc1b,
        const float* fc2w, const float* fc2b, const int* flags, void* outp) {
    int g = blockIdx.x;
    int t = threadIdx.x;
    int q = t >> 6, w = t & 63;
    int s = gstart[g], e = gstart[g + 1];
    float a0 = 0.f, a1 = 0.f;
    #pragma unroll 4
    for (int n = s + q; n < e; n += 4) {
        unsigned int h = Hb[(size_t)n * FDH + w];
        a0 += bflo(h);
        a1 += bfhi(h);
    }
    __shared__ float pp[4][FD];
    __shared__ float z[FD + FA];
    __shared__ float h[FD];
    pp[q][2 * w]     = a0;
    pp[q][2 * w + 1] = a1;
    __syncthreads();
    if (t < FD) {
        float cnt = (float)(e - s);
        if (cnt < 1.0f) cnt = 1.0f;
        z[t] = (pp[0][t] + pp[1][t] + pp[2][t] + pp[3][t]) / cnt;
    }
    if (t >= FD && t < FD + FA) z[t] = addf[g * FA + (t - FD)];
    __syncthreads();
    if (t < FD) {
        float acc = fc1b[t];
        #pragma unroll 4
        for (int k = 0; k < FD + FA; ++k)
            acc += z[k] * fc1w[k * FD + t];
        h[t] = fmaxf(acc, 0.f);
    }
    __syncthreads();
    if (t < 2) {
        float o = fc2b[t];
        for (int j = 0; j < FD; ++j) o += h[j] * fc2w[j * 2 + t];
        if (flags[0]) ((unsigned short*)outp)[g * 2 + t] = f2bf(o);
        else          ((float*)outp)[g * 2 + t] = o;
    }
}

extern "C" void kernel_launch(void* const* d_in, const int* in_sizes, int n_in,
                              void* d_out, int out_size, void* d_ws, size_t ws_size,
                              hipStream_t stream) {
    (void)out_size;

    if (n_in != 12) {
        hipLaunchKernelGGL(mark_kernel, dim3(1), dim3(128), 0, stream,
                           (float*)d_out, 2000.0f);
        return;
    }
    const int exp_sizes[12] = {6400000, 1600000, 50000, 4096, 16384, 128,
                               16384, 128, 20480, 128, 256, 2};
    for (int i = 0; i < 12; ++i) {
        if (in_sizes[i] != exp_sizes[i]) {
            hipLaunchKernelGGL(mark_kernel, dim3(1), dim3(128), 0, stream,
                               (float*)d_out, 3000.0f + 100.0f * i);
            return;
        }
    }

    size_t off = 0;
    char* base = (char*)d_ws;
#define WSALLOC(ptr, type, nbytes) \
    type* ptr = (type*)(base + off); off += (((size_t)(nbytes)) + 255) & ~(size_t)255;
    WSALLOC(bufA,  unsigned int, (size_t)NN * FDH * 4)
    WSALLOC(bufB,  unsigned int, (size_t)NN * FDH * 4)
    WSALLOC(dinv,  float, (size_t)NN * 4)
    WSALLOC(degi,  int,   (size_t)NN * 4)
    WSALLOC(rowst, int,   (size_t)(NN + 1) * 4)
    WSALLOC(cursor,int,   (size_t)NN * 4)
    WSALLOC(escan, int,   (size_t)NN * 4)
    WSALLOC(bsum,  int,   (size_t)NBLK * 4)
    WSALLOC(cv,    unsigned int, (size_t)EETOT * 4)
    WSALLOC(gstart,int,   (size_t)(NG + 1) * 4)
    WSALLOC(s32,   int,   (size_t)NE * 4)
    WSALLOC(d32,   int,   (size_t)NE * 4)
    WSALLOC(W1t,   unsigned int, (size_t)FD * FDH * 4)
    WSALLOC(W2t,   unsigned int, (size_t)FD * FDH * 4)
    WSALLOC(b1f,   float, FD * 4)
    WSALLOC(b2f,   float, FD * 4)
    WSALLOC(addff, float, (size_t)NG * FA * 4)
    WSALLOC(fc1wf, float, (size_t)(FD + FA) * FD * 4)
    WSALLOC(fc1bf, float, FD * 4)
    WSALLOC(fc2wf, float, FD * 2 * 4)
    WSALLOC(fc2bf, float, 2 * 4)
    WSALLOC(flags, int, 16 * 4)
#undef WSALLOC
    if (ws_size < off) {
        hipLaunchKernelGGL(mark_kernel, dim3(1), dim3(128), 0, stream,
                           (float*)d_out, 1000.0f);
        return;
    }

    const int* ei    = (const int*)d_in[1];
    const int* batch = (const int*)d_in[2];

    hipLaunchKernelGGL(flags_kernel, dim3(1), dim3(256), 0, stream,
                       (const unsigned int*)d_in[0], ei, batch,
                       (const unsigned int*)d_in[3], (const unsigned int*)d_in[4],
                       (const unsigned int*)d_in[5], (const unsigned int*)d_in[6],
                       (const unsigned int*)d_in[7], (const unsigned int*)d_in[8],
                       (const unsigned int*)d_in[9], (const unsigned int*)d_in[10],
                       (const unsigned int*)d_in[11], flags);

    hipLaunchKernelGGL(prep, dim3(359), dim3(256), 0, stream,
                       d_in[3], d_in[4], d_in[5], d_in[6], d_in[7],
                       d_in[8], d_in[9], d_in[10], d_in[11],
                       W1t, W2t, addff, b1f, b2f, fc1wf, fc1bf,
                       fc2wf, fc2bf, flags, degi);

    hipLaunchKernelGGL(deg_kernel, dim3((NE + 255) / 256), dim3(256), 0, stream,
                       ei, flags, degi, s32, d32);
    hipLaunchKernelGGL(scan1, dim3(NBLK), dim3(256), 0, stream,
                       degi, dinv, escan, bsum);
    hipLaunchKernelGGL(scan3, dim3(NBLK), dim3(256), 0, stream,
                       escan, bsum, batch, flags, rowst, cursor, gstart);
    hipLaunchKernelGGL(fill_kernel, dim3(FNCH * 8), dim3(256), 0, stream,
                       s32, d32, dinv, cursor, cv);

    hipLaunchKernelGGL(gemm_mfma, dim3((NN + 63) / 64), dim3(256), 0, stream,
                       d_in[0], W1t, (unsigned short*)bufA, flags, 1);
    hipLaunchKernelGGL(aggregate_kernel, dim3((NN + 3) / 4), dim3(256), 0, stream,
                       bufA, cv, rowst, b1f, bufB);
    hipLaunchKernelGGL(gemm_mfma, dim3((NN + 63) / 64), dim3(256), 0, stream,
                       bufB, W2t, (unsigned short*)bufA, flags, 0);
    hipLaunchKernelGGL(aggregate_kernel, dim3((NN + 3) / 4), dim3(256), 0, stream,
                       bufA, cv, rowst, b2f, bufB);

    hipLaunchKernelGGL(poolhead, dim3(NG), dim3(256), 0, stream,
                       bufB, gstart, addff, fc1wf, fc1bf, fc2wf, fc2bf,
                       flags, d_out);
}